// Round 1
// baseline (2070.444 us; speedup 1.0000x reference)
//
#include <hip/hip_runtime.h>
#include <hip/hip_bf16.h>

#define NN 768
#define CSD 384
#define CZD 128
#define ED 16
#define PQD 4
#define PVD 8
#define HD 12
#define DOUT 2112

#define SCALE_SINGLE 0.25f
#define SCALE_FRAME (-0.11785113019775793f)   /* -1/sqrt(72) */

__device__ __forceinline__ float dot4f(float4 a, float4 b){
    return fmaf(a.x,b.x, fmaf(a.y,b.y, fmaf(a.z,b.z, a.w*b.w)));
}

// ---------------- K1: projections + frame apply ----------------
__global__ __launch_bounds__(384) void k_proj(
    const float* __restrict__ s, const float* __restrict__ R, const float* __restrict__ tv,
    const float* __restrict__ Wq, const float* __restrict__ Wk, const float* __restrict__ Wv,
    const float* __restrict__ Wqp, const float* __restrict__ Wkp, const float* __restrict__ Wvp,
    float* __restrict__ q, float* __restrict__ k, float* __restrict__ v,
    float* __restrict__ gq, float* __restrict__ gk, float* __restrict__ gv,
    float* __restrict__ sqq, float* __restrict__ sqk)
{
    __shared__ float s_l[CSD];
    __shared__ float praw[576];    // qp(144) kp(144) vp(288) raw local coords
    __shared__ float sq_pt[96];    // per-point squared norms (48 q, 48 k)
    int i = blockIdx.x, t = threadIdx.x;
    s_l[t] = s[(size_t)i*CSD + t];
    __syncthreads();

    int cols[3] = {t, t+384, t+768};
    const float* Wp[3]; int st[3], lc[3];
    #pragma unroll
    for (int m=0;m<3;m++){
        int c = cols[m];
        if (c < 192){ Wp[m]=Wq;  st[m]=192; lc[m]=c; }
        else if (c < 384){ Wp[m]=Wk;  st[m]=192; lc[m]=c-192; }
        else if (c < 576){ Wp[m]=Wv;  st[m]=192; lc[m]=c-384; }
        else if (c < 720){ Wp[m]=Wqp; st[m]=144; lc[m]=c-576; }
        else if (c < 864){ Wp[m]=Wkp; st[m]=144; lc[m]=c-720; }
        else { Wp[m]=Wvp; st[m]=288; lc[m]=c-864; }
    }
    float a0=0.f,a1=0.f,a2=0.f;
    for (int r=0;r<CSD;r++){
        float sv = s_l[r];
        a0 = fmaf(sv, Wp[0][(size_t)r*st[0]+lc[0]], a0);
        a1 = fmaf(sv, Wp[1][(size_t)r*st[1]+lc[1]], a1);
        a2 = fmaf(sv, Wp[2][(size_t)r*st[2]+lc[2]], a2);
    }
    float av[3] = {a0,a1,a2};
    #pragma unroll
    for (int m=0;m<3;m++){
        int c = cols[m]; float val = av[m];
        if (c < 192) q[(size_t)i*192 + c] = val;
        else if (c < 384) k[(size_t)i*192 + (c-192)] = val;
        else if (c < 576) v[(size_t)i*192 + (c-384)] = val;
        else praw[c-576] = val;
    }
    __syncthreads();

    if (t < 192){
        const float* Ri = R + (size_t)i*9;
        float R00=Ri[0],R01=Ri[1],R02=Ri[2];
        float R10=Ri[3],R11=Ri[4],R12=Ri[5];
        float R20=Ri[6],R21=Ri[7],R22=Ri[8];
        float t0=tv[(size_t)i*3+0],t1=tv[(size_t)i*3+1],t2=tv[(size_t)i*3+2];
        int src; float* dst; int sqslot=-1;
        if (t < 48){ src = t*3; dst = gq + (size_t)i*144 + t*3; sqslot = t; }
        else if (t < 96){ int u=t-48; src = 144+u*3; dst = gk + (size_t)i*144 + u*3; sqslot = 48+u; }
        else { int u=t-96; src = 288+u*3; dst = gv + (size_t)i*288 + u*3; }
        float x=praw[src], y=praw[src+1], zc=praw[src+2];
        float g0 = fmaf(R00,x, fmaf(R01,y, fmaf(R02,zc, t0)));
        float g1 = fmaf(R10,x, fmaf(R11,y, fmaf(R12,zc, t1)));
        float g2 = fmaf(R20,x, fmaf(R21,y, fmaf(R22,zc, t2)));
        dst[0]=g0; dst[1]=g1; dst[2]=g2;
        if (sqslot >= 0) sq_pt[sqslot] = g0*g0 + g1*g1 + g2*g2;
    }
    __syncthreads();
    if (t < HD){
        float s1 = sq_pt[t*4]+sq_pt[t*4+1]+sq_pt[t*4+2]+sq_pt[t*4+3];
        float s2 = sq_pt[48+t*4]+sq_pt[48+t*4+1]+sq_pt[48+t*4+2]+sq_pt[48+t*4+3];
        sqq[(size_t)i*HD + t] = s1;
        sqk[(size_t)i*HD + t] = s2;
    }
}

// ---------------- K2: logits (single+pair+frame) + softmax ----------------
__global__ __launch_bounds__(256) void k_logits(
    const float* __restrict__ z, const float* __restrict__ Wb, const float* __restrict__ scale_head,
    const float* __restrict__ q, const float* __restrict__ k,
    const float* __restrict__ gq, const float* __restrict__ gk,
    const float* __restrict__ sqq, const float* __restrict__ sqk,
    float* __restrict__ a)
{
    __shared__ float wbT[HD*CZD];   // [h][c]
    int i = blockIdx.x, t = threadIdx.x;
    int wave = t >> 6, lane = t & 63;
    int h0 = wave * 3;

    for (int idx=t; idx<HD*CZD; idx+=256){
        int h = idx >> 7, c = idx & 127;
        wbT[idx] = Wb[(size_t)c*HD + h];
    }
    // per-thread (3 heads) constants in registers
    float4 qf[3][4]; float4 gqf[3][3]; float sqq3[3], sp3[3];
    #pragma unroll
    for (int hs=0;hs<3;hs++){
        int h = h0+hs;
        const float4* qp = (const float4*)(q + (size_t)i*192 + h*16);
        qf[hs][0]=qp[0]; qf[hs][1]=qp[1]; qf[hs][2]=qp[2]; qf[hs][3]=qp[3];
        const float4* gp = (const float4*)(gq + (size_t)i*144 + h*12);
        gqf[hs][0]=gp[0]; gqf[hs][1]=gp[1]; gqf[hs][2]=gp[2];
        sqq3[hs] = sqq[(size_t)i*HD + h];
        float shv = scale_head[h];
        float sp = (shv > 20.f) ? shv : log1pf(__expf(shv));
        sp3[hs] = SCALE_FRAME * sp;
    }
    __syncthreads();

    float L[12][3];
    const float4* wb4 = (const float4*)wbT;   // [h][c4] of float4, stride 32 per h
    #pragma unroll
    for (int tile=0; tile<12; tile++){
        int j = tile*64 + lane;
        const float4* zp  = (const float4*)z + ((size_t)i*NN + j)*32;
        const float4* kp  = (const float4*)(k  + (size_t)j*192);
        const float4* gkp = (const float4*)(gk + (size_t)j*144);
        float accP[3] = {0.f,0.f,0.f};
        #pragma unroll 8
        for (int c4=0;c4<32;c4++){
            float4 zv = zp[c4];
            accP[0] += dot4f(zv, wb4[(h0+0)*32 + c4]);
            accP[1] += dot4f(zv, wb4[(h0+1)*32 + c4]);
            accP[2] += dot4f(zv, wb4[(h0+2)*32 + c4]);
        }
        #pragma unroll
        for (int hs=0;hs<3;hs++){
            int h = h0+hs;
            float sng = dot4f(qf[hs][0], kp[h*4+0]) + dot4f(qf[hs][1], kp[h*4+1])
                      + dot4f(qf[hs][2], kp[h*4+2]) + dot4f(qf[hs][3], kp[h*4+3]);
            float fdot = dot4f(gqf[hs][0], gkp[h*3+0]) + dot4f(gqf[hs][1], gkp[h*3+1])
                       + dot4f(gqf[hs][2], gkp[h*3+2]);
            float d2 = sqq3[hs] + sqk[(size_t)j*HD + h] - 2.0f*fdot;
            L[tile][hs] = fmaf(SCALE_SINGLE, sng, accP[hs]) + sp3[hs]*d2;
        }
    }
    // in-wave softmax over j (row length 768 = 12 tiles x 64 lanes)
    float inv[3];
    #pragma unroll
    for (int hs=0;hs<3;hs++){
        float m = -1e30f;
        #pragma unroll
        for (int tile=0;tile<12;tile++) m = fmaxf(m, L[tile][hs]);
        #pragma unroll
        for (int off=32; off; off>>=1) m = fmaxf(m, __shfl_xor(m, off));
        float ssum = 0.f;
        #pragma unroll
        for (int tile=0;tile<12;tile++){ float e = __expf(L[tile][hs]-m); L[tile][hs]=e; ssum += e; }
        #pragma unroll
        for (int off=32; off; off>>=1) ssum += __shfl_xor(ssum, off);
        inv[hs] = 1.0f/ssum;
    }
    #pragma unroll
    for (int tile=0;tile<12;tile++){
        int j = tile*64 + lane;
        #pragma unroll
        for (int hs=0;hs<3;hs++){
            a[((size_t)(h0+hs)*NN + i)*NN + j] = L[tile][hs]*inv[hs];
        }
    }
}

// ---------------- K3: o_z, o_s, so + inverse frame + att assembly ----------------
__global__ __launch_bounds__(512) void k_outputs(
    const float* __restrict__ a, const float* __restrict__ z,
    const float* __restrict__ v, const float* __restrict__ gv,
    const float* __restrict__ R, const float* __restrict__ tv,
    float* __restrict__ att)
{
    __shared__ float so_l[288];
    int i = blockIdx.x, t = threadIdx.x;
    if (t < 384){
        // o_z: 12 heads x 32 float4 lanes
        int h = t >> 5, c4 = t & 31;
        const float* arow = a + ((size_t)h*NN + i)*NN;
        const float4* zp = (const float4*)z + (size_t)i*NN*32 + c4;
        float4 acc = {0.f,0.f,0.f,0.f};
        for (int j=0;j<NN;j++){
            float av = arow[j];
            float4 zv = zp[(size_t)j*32];
            acc.x = fmaf(av, zv.x, acc.x);
            acc.y = fmaf(av, zv.y, acc.y);
            acc.z = fmaf(av, zv.z, acc.z);
            acc.w = fmaf(av, zv.w, acc.w);
        }
        float4* dst = (float4*)(att + (size_t)i*DOUT + 192 + h*128) + c4;
        *dst = acc;
    } else {
        // o_s (192 outputs) + so (288 outputs) handled by 128 threads x up to 4 outputs
        int u = t - 384;
        float acc[4] = {0.f,0.f,0.f,0.f};
        const float* src[4]; const float* ar[4]; int stv[4]; bool ok[4];
        #pragma unroll
        for (int r=0;r<4;r++){
            int o = u + r*128; ok[r] = false; src[r]=v; ar[r]=a; stv[r]=192;
            if (o < 192){ int h=o>>4, e=o&15; src[r] = v + h*16+e; stv[r]=192;
                          ar[r] = a + ((size_t)h*NN+i)*NN; ok[r]=true; }
            else if (o < 480){ int o2=o-192; int h=o2/24, pc=o2%24;
                          src[r] = gv + h*24+pc; stv[r]=288;
                          ar[r] = a + ((size_t)h*NN+i)*NN; ok[r]=true; }
        }
        for (int j=0;j<NN;j++){
            #pragma unroll
            for (int r=0;r<4;r++) if (ok[r]) acc[r] = fmaf(ar[r][j], src[r][(size_t)j*stv[r]], acc[r]);
        }
        #pragma unroll
        for (int r=0;r<4;r++){
            int o = u + r*128;
            if (!ok[r]) continue;
            if (o < 192) att[(size_t)i*DOUT + o] = acc[r];
            else so_l[o-192] = acc[r];
        }
    }
    __syncthreads();
    if (t < 96){
        int h = t >> 3, p = t & 7;
        float d0 = so_l[h*24+p*3+0] - tv[(size_t)i*3+0];
        float d1 = so_l[h*24+p*3+1] - tv[(size_t)i*3+1];
        float d2 = so_l[h*24+p*3+2] - tv[(size_t)i*3+2];
        const float* Ri = R + (size_t)i*9;
        // local[a] = sum_b R[b][a] * d[b]   (R^T)
        float l0 = fmaf(Ri[0],d0, fmaf(Ri[3],d1, Ri[6]*d2));
        float l1 = fmaf(Ri[1],d0, fmaf(Ri[4],d1, Ri[7]*d2));
        float l2 = fmaf(Ri[2],d0, fmaf(Ri[5],d1, Ri[8]*d2));
        size_t base = (size_t)i*DOUT;
        att[base + 1728 + p*36 + h*3 + 0] = l0;
        att[base + 1728 + p*36 + h*3 + 1] = l1;
        att[base + 1728 + p*36 + h*3 + 2] = l2;
        att[base + 2016 + p*12 + h] = sqrtf(l0*l0 + l1*l1 + l2*l2);
    }
}

// ---------------- K4: final projection att @ Wout + bout ----------------
#define ROWS4 2
__global__ __launch_bounds__(384) void k_final(
    const float* __restrict__ att, const float* __restrict__ Wout, const float* __restrict__ bout,
    float* __restrict__ out)
{
    __shared__ float att_l[ROWS4*DOUT];
    int ib = blockIdx.x * ROWS4, t = threadIdx.x;
    for (int idx=t; idx<ROWS4*DOUT; idx+=384){
        att_l[idx] = att[(size_t)ib*DOUT + idx];
    }
    __syncthreads();
    float b = bout[t];
    float acc0 = b, acc1 = b;
    #pragma unroll 4
    for (int d=0; d<DOUT; d++){
        float w = Wout[(size_t)d*384 + t];
        acc0 = fmaf(att_l[d],      w, acc0);
        acc1 = fmaf(att_l[DOUT+d], w, acc1);
    }
    out[(size_t)ib*384 + t] = acc0;
    out[(size_t)(ib+1)*384 + t] = acc1;
}

extern "C" void kernel_launch(void* const* d_in, const int* in_sizes, int n_in,
                              void* d_out, int out_size, void* d_ws, size_t ws_size,
                              hipStream_t stream)
{
    const float* s   = (const float*)d_in[0];
    const float* z   = (const float*)d_in[1];
    const float* R   = (const float*)d_in[2];
    const float* tv  = (const float*)d_in[3];
    const float* Wq  = (const float*)d_in[4];
    const float* Wk  = (const float*)d_in[5];
    const float* Wv  = (const float*)d_in[6];
    const float* Wqp = (const float*)d_in[7];
    const float* Wkp = (const float*)d_in[8];
    const float* Wvp = (const float*)d_in[9];
    const float* Wb  = (const float*)d_in[10];
    const float* Wout= (const float*)d_in[11];
    const float* bout= (const float*)d_in[12];
    const float* sh  = (const float*)d_in[13];

    float* ws  = (float*)d_ws;
    float* q_  = ws;                 // 768*192
    float* k_  = q_  + 147456;       // 768*192
    float* v_  = k_  + 147456;       // 768*192
    float* gq_ = v_  + 147456;       // 768*144
    float* gk_ = gq_ + 110592;       // 768*144
    float* gv_ = gk_ + 110592;       // 768*288
    float* sqq_= gv_ + 221184;       // 768*12
    float* sqk_= sqq_ + 9216;        // 768*12
    float* a_  = sqk_ + 9216;        // 12*768*768
    float* att_= a_  + 7077888;      // 768*2112
    float* out = (float*)d_out;

    hipLaunchKernelGGL(k_proj,    dim3(NN),  dim3(384), 0, stream,
                       s,R,tv,Wq,Wk,Wv,Wqp,Wkp,Wvp, q_,k_,v_,gq_,gk_,gv_,sqq_,sqk_);
    hipLaunchKernelGGL(k_logits,  dim3(NN),  dim3(256), 0, stream,
                       z,Wb,sh,q_,k_,gq_,gk_,sqq_,sqk_, a_);
    hipLaunchKernelGGL(k_outputs, dim3(NN),  dim3(512), 0, stream,
                       a_,z,v_,gv_,R,tv, att_);
    hipLaunchKernelGGL(k_final,   dim3(NN/ROWS4), dim3(384), 0, stream,
                       att_,Wout,bout, out);
}

// Round 2
// 936.022 us; speedup vs baseline: 2.2120x; 2.2120x over previous
//
#include <hip/hip_runtime.h>
#include <hip/hip_bf16.h>

#define NN 768
#define CSD 384
#define CZD 128
#define HD 12
#define DOUT 2112

#define SCALE_SINGLE 0.25f
#define SCALE_FRAME (-0.11785113019775793f)   /* -1/sqrt(72) */

__device__ __forceinline__ float dot4f(float4 a, float4 b){
    return fmaf(a.x,b.x, fmaf(a.y,b.y, fmaf(a.z,b.z, a.w*b.w)));
}

// ---------------- K1: projections + frame apply ----------------
__global__ __launch_bounds__(384) void k_proj(
    const float* __restrict__ s, const float* __restrict__ R, const float* __restrict__ tv,
    const float* __restrict__ Wq, const float* __restrict__ Wk, const float* __restrict__ Wv,
    const float* __restrict__ Wqp, const float* __restrict__ Wkp, const float* __restrict__ Wvp,
    float* __restrict__ q, float* __restrict__ k, float* __restrict__ v,
    float* __restrict__ gq, float* __restrict__ gk, float* __restrict__ gv,
    float* __restrict__ sqq, float* __restrict__ sqk)
{
    __shared__ float s_l[CSD];
    __shared__ float praw[576];    // qp(144) kp(144) vp(288) raw local coords
    __shared__ float sq_pt[96];    // per-point squared norms (48 q, 48 k)
    int i = blockIdx.x, t = threadIdx.x;
    s_l[t] = s[(size_t)i*CSD + t];
    __syncthreads();

    int cols[3] = {t, t+384, t+768};
    const float* Wp[3]; int st[3], lc[3];
    #pragma unroll
    for (int m=0;m<3;m++){
        int c = cols[m];
        if (c < 192){ Wp[m]=Wq;  st[m]=192; lc[m]=c; }
        else if (c < 384){ Wp[m]=Wk;  st[m]=192; lc[m]=c-192; }
        else if (c < 576){ Wp[m]=Wv;  st[m]=192; lc[m]=c-384; }
        else if (c < 720){ Wp[m]=Wqp; st[m]=144; lc[m]=c-576; }
        else if (c < 864){ Wp[m]=Wkp; st[m]=144; lc[m]=c-720; }
        else { Wp[m]=Wvp; st[m]=288; lc[m]=c-864; }
    }
    float a0=0.f,a1=0.f,a2=0.f;
    #pragma unroll 8
    for (int r=0;r<CSD;r++){
        float sv = s_l[r];
        a0 = fmaf(sv, Wp[0][(size_t)r*st[0]+lc[0]], a0);
        a1 = fmaf(sv, Wp[1][(size_t)r*st[1]+lc[1]], a1);
        a2 = fmaf(sv, Wp[2][(size_t)r*st[2]+lc[2]], a2);
    }
    float av[3] = {a0,a1,a2};
    #pragma unroll
    for (int m=0;m<3;m++){
        int c = cols[m]; float val = av[m];
        if (c < 192) q[(size_t)i*192 + c] = val;
        else if (c < 384) k[(size_t)i*192 + (c-192)] = val;
        else if (c < 576) v[(size_t)i*192 + (c-384)] = val;
        else praw[c-576] = val;
    }
    __syncthreads();

    if (t < 192){
        const float* Ri = R + (size_t)i*9;
        float R00=Ri[0],R01=Ri[1],R02=Ri[2];
        float R10=Ri[3],R11=Ri[4],R12=Ri[5];
        float R20=Ri[6],R21=Ri[7],R22=Ri[8];
        float t0=tv[(size_t)i*3+0],t1=tv[(size_t)i*3+1],t2=tv[(size_t)i*3+2];
        int src; float* dst; int sqslot=-1;
        if (t < 48){ src = t*3; dst = gq + (size_t)i*144 + t*3; sqslot = t; }
        else if (t < 96){ int u=t-48; src = 144+u*3; dst = gk + (size_t)i*144 + u*3; sqslot = 48+u; }
        else { int u=t-96; src = 288+u*3; dst = gv + (size_t)i*288 + u*3; }
        float x=praw[src], y=praw[src+1], zc=praw[src+2];
        float g0 = fmaf(R00,x, fmaf(R01,y, fmaf(R02,zc, t0)));
        float g1 = fmaf(R10,x, fmaf(R11,y, fmaf(R12,zc, t1)));
        float g2 = fmaf(R20,x, fmaf(R21,y, fmaf(R22,zc, t2)));
        dst[0]=g0; dst[1]=g1; dst[2]=g2;
        if (sqslot >= 0) sq_pt[sqslot] = g0*g0 + g1*g1 + g2*g2;
    }
    __syncthreads();
    if (t < HD){
        float s1 = sq_pt[t*4]+sq_pt[t*4+1]+sq_pt[t*4+2]+sq_pt[t*4+3];
        float s2 = sq_pt[48+t*4]+sq_pt[48+t*4+1]+sq_pt[48+t*4+2]+sq_pt[48+t*4+3];
        sqq[(size_t)i*HD + t] = s1;
        sqk[(size_t)i*HD + t] = s2;
    }
}

// ---------------- K2: logits (single+pair+frame) + softmax ----------------
__global__ __launch_bounds__(256) void k_logits(
    const float* __restrict__ z, const float* __restrict__ Wb, const float* __restrict__ scale_head,
    const float* __restrict__ q, const float* __restrict__ k,
    const float* __restrict__ gq, const float* __restrict__ gk,
    const float* __restrict__ sqq, const float* __restrict__ sqk,
    float* __restrict__ a)
{
    __shared__ float wbT[HD*CZD];   // [h][c]
    int i = blockIdx.x, t = threadIdx.x;
    int wave = t >> 6, lane = t & 63;
    int h0 = wave * 3;

    for (int idx=t; idx<HD*CZD; idx+=256){
        int h = idx >> 7, c = idx & 127;
        wbT[idx] = Wb[(size_t)c*HD + h];
    }
    // per-thread (3 heads) constants in registers
    float4 qf[3][4]; float4 gqf[3][3]; float sqq3[3], sp3[3];
    #pragma unroll
    for (int hs=0;hs<3;hs++){
        int h = h0+hs;
        const float4* qp = (const float4*)(q + (size_t)i*192 + h*16);
        qf[hs][0]=qp[0]; qf[hs][1]=qp[1]; qf[hs][2]=qp[2]; qf[hs][3]=qp[3];
        const float4* gp = (const float4*)(gq + (size_t)i*144 + h*12);
        gqf[hs][0]=gp[0]; gqf[hs][1]=gp[1]; gqf[hs][2]=gp[2];
        sqq3[hs] = sqq[(size_t)i*HD + h];
        float shv = scale_head[h];
        float sp = (shv > 20.f) ? shv : log1pf(__expf(shv));
        sp3[hs] = SCALE_FRAME * sp;
    }
    __syncthreads();

    float L[12][3];
    const float4* wb4 = (const float4*)wbT;   // [h][c4] of float4, stride 32 per h
    #pragma unroll
    for (int tile=0; tile<12; tile++){
        int j = tile*64 + lane;
        const float4* zp  = (const float4*)z + ((size_t)i*NN + j)*32;
        const float4* kp  = (const float4*)(k  + (size_t)j*192);
        const float4* gkp = (const float4*)(gk + (size_t)j*144);
        float accP[3] = {0.f,0.f,0.f};
        #pragma unroll 8
        for (int c4=0;c4<32;c4++){
            float4 zv = zp[c4];
            accP[0] += dot4f(zv, wb4[(h0+0)*32 + c4]);
            accP[1] += dot4f(zv, wb4[(h0+1)*32 + c4]);
            accP[2] += dot4f(zv, wb4[(h0+2)*32 + c4]);
        }
        #pragma unroll
        for (int hs=0;hs<3;hs++){
            int h = h0+hs;
            float sng = dot4f(qf[hs][0], kp[h*4+0]) + dot4f(qf[hs][1], kp[h*4+1])
                      + dot4f(qf[hs][2], kp[h*4+2]) + dot4f(qf[hs][3], kp[h*4+3]);
            float fdot = dot4f(gqf[hs][0], gkp[h*3+0]) + dot4f(gqf[hs][1], gkp[h*3+1])
                       + dot4f(gqf[hs][2], gkp[h*3+2]);
            float d2 = sqq3[hs] + sqk[(size_t)j*HD + h] - 2.0f*fdot;
            L[tile][hs] = fmaf(SCALE_SINGLE, sng, accP[hs]) + sp3[hs]*d2;
        }
    }
    // in-wave softmax over j (row length 768 = 12 tiles x 64 lanes)
    float inv[3];
    #pragma unroll
    for (int hs=0;hs<3;hs++){
        float m = -1e30f;
        #pragma unroll
        for (int tile=0;tile<12;tile++) m = fmaxf(m, L[tile][hs]);
        #pragma unroll
        for (int off=32; off; off>>=1) m = fmaxf(m, __shfl_xor(m, off));
        float ssum = 0.f;
        #pragma unroll
        for (int tile=0;tile<12;tile++){ float e = __expf(L[tile][hs]-m); L[tile][hs]=e; ssum += e; }
        #pragma unroll
        for (int off=32; off; off>>=1) ssum += __shfl_xor(ssum, off);
        inv[hs] = 1.0f/ssum;
    }
    #pragma unroll
    for (int tile=0;tile<12;tile++){
        int j = tile*64 + lane;
        #pragma unroll
        for (int hs=0;hs<3;hs++){
            a[((size_t)(h0+hs)*NN + i)*NN + j] = L[tile][hs]*inv[hs];
        }
    }
}

// ---------------- K3: o_z, o_s, so via LDS-staged tiles ----------------
// block = one i, 512 threads.
// LDS: a_l[12][768] (36KB) + ztile dbuf 2x32x128 (32KB) + so_l (1.2KB) = 70KB -> 2 blocks/CU
__global__ __launch_bounds__(512) void k_outputs(
    const float* __restrict__ a, const float* __restrict__ z,
    const float* __restrict__ v, const float* __restrict__ gv,
    const float* __restrict__ R, const float* __restrict__ tv,
    float* __restrict__ att)
{
    __shared__ float a_l[HD][NN];
    __shared__ float ztile[2][32][CZD];
    __shared__ float so_l[288];
    int i = blockIdx.x, t = threadIdx.x;

    // stage a rows (12 x 768 floats = 2304 f4), coalesced
    {
        float4* a_l4 = (float4*)&a_l[0][0];
        const float4* a4 = (const float4*)a;
        #pragma unroll
        for (int r=0;r<5;r++){
            int idx = t + r*512;
            if (idx < 2304){
                int h = idx/192, c = idx - h*192;
                a_l4[idx] = a4[(size_t)(h*NN + i)*192 + c];
            }
        }
    }

    const float* zi = z + (size_t)i*NN*CZD;

    // async stage one 32-row z tile (16KB = 1024 f4, 512 threads x 2)
#define STAGE(JT, BUF) do { \
    const float* _s = zi + (size_t)(JT)*4096 + t*4; \
    float* _d = &ztile[BUF][0][0] + t*4; \
    __builtin_amdgcn_global_load_lds((const __attribute__((address_space(1))) void*)_s, \
        (__attribute__((address_space(3))) void*)_d, 16, 0, 0); \
    __builtin_amdgcn_global_load_lds((const __attribute__((address_space(1))) void*)(_s+2048), \
        (__attribute__((address_space(3))) void*)(_d+2048), 16, 0, 0); \
  } while(0)

    STAGE(0, 0);

    // slot assignment
    int hs = 0;
    const float4* gsrc = nullptr;  // for o_s / so global-stream slots
    int gstride = 0;
    if (t < 384){ hs = t>>5; }
    else if (t < 432){ int u=t-384; hs = u>>2; gsrc = (const float4*)v  + hs*4 + (u&3); gstride = 48; }
    else if (t < 504){ int u=t-432; hs = u/6;  gsrc = (const float4*)gv + hs*6 + (u%6); gstride = 72; }
    float4 acc = {0.f,0.f,0.f,0.f};
    int c4 = t & 31;

    __syncthreads();   // a_l visible; barrier drains STAGE(0)

    for (int jt=0; jt<24; ++jt){
        int cur = jt & 1;
        if (jt+1 < 24) STAGE(jt+1, cur^1);   // prefetch overlaps compute below
        if (t < 384){
            const float4* arow4 = (const float4*)&a_l[hs][0];
            float4 af[8];
            #pragma unroll
            for (int m=0;m<8;m++) af[m] = arow4[jt*8 + m];
            const float4* zt4 = (const float4*)&ztile[cur][0][0];
            #pragma unroll
            for (int jj=0;jj<32;jj++){
                float aw = ((const float*)af)[jj];
                float4 zv = zt4[jj*32 + c4];
                acc.x = fmaf(aw, zv.x, acc.x);
                acc.y = fmaf(aw, zv.y, acc.y);
                acc.z = fmaf(aw, zv.z, acc.z);
                acc.w = fmaf(aw, zv.w, acc.w);
            }
        } else if (t < 504){
            const float* arow = &a_l[hs][0];
            #pragma unroll
            for (int jj=0;jj<32;jj++){
                int j = jt*32 + jj;
                float aw = arow[j];
                float4 sv = gsrc[(size_t)j*gstride];
                acc.x = fmaf(aw, sv.x, acc.x);
                acc.y = fmaf(aw, sv.y, acc.y);
                acc.z = fmaf(aw, sv.z, acc.z);
                acc.w = fmaf(aw, sv.w, acc.w);
            }
        }
        __syncthreads();   // compute(cur) done + prefetch drained
    }

    // epilogue: write results
    if (t < 384){
        float4* dst = (float4*)(att + (size_t)i*DOUT + 192) + (hs*32 + c4);
        *dst = acc;
    } else if (t < 432){
        int u = t-384;
        float4* dst = (float4*)(att + (size_t)i*DOUT) + u;
        *dst = acc;
    } else if (t < 504){
        int u = t-432;
        ((float4*)so_l)[u] = acc;
    }
    __syncthreads();
    if (t < 96){
        int h = t >> 3, p = t & 7;
        float d0 = so_l[h*24+p*3+0] - tv[(size_t)i*3+0];
        float d1 = so_l[h*24+p*3+1] - tv[(size_t)i*3+1];
        float d2 = so_l[h*24+p*3+2] - tv[(size_t)i*3+2];
        const float* Ri = R + (size_t)i*9;
        float l0 = fmaf(Ri[0],d0, fmaf(Ri[3],d1, Ri[6]*d2));
        float l1 = fmaf(Ri[1],d0, fmaf(Ri[4],d1, Ri[7]*d2));
        float l2 = fmaf(Ri[2],d0, fmaf(Ri[5],d1, Ri[8]*d2));
        size_t base = (size_t)i*DOUT;
        att[base + 1728 + p*36 + h*3 + 0] = l0;
        att[base + 1728 + p*36 + h*3 + 1] = l1;
        att[base + 1728 + p*36 + h*3 + 2] = l2;
        att[base + 2016 + p*12 + h] = sqrtf(l0*l0 + l1*l1 + l2*l2);
    }
#undef STAGE
}

// ---------------- K4: final projection att @ Wout + bout ----------------
#define ROWS4 2
__global__ __launch_bounds__(384) void k_final(
    const float* __restrict__ att, const float* __restrict__ Wout, const float* __restrict__ bout,
    float* __restrict__ out)
{
    __shared__ float att_l[ROWS4*DOUT];
    int ib = blockIdx.x * ROWS4, t = threadIdx.x;
    for (int idx=t; idx<ROWS4*DOUT; idx+=384){
        att_l[idx] = att[(size_t)ib*DOUT + idx];
    }
    __syncthreads();
    // 4 independent chains per row -> up to 16 loads in flight
    float a0=0.f,a1=0.f,a2=0.f,a3=0.f;
    float b0=0.f,b1=0.f,b2=0.f,b3=0.f;
    #pragma unroll 4
    for (int d=0; d<DOUT; d+=4){
        float w0 = Wout[(size_t)(d+0)*CSD + t];
        float w1 = Wout[(size_t)(d+1)*CSD + t];
        float w2 = Wout[(size_t)(d+2)*CSD + t];
        float w3 = Wout[(size_t)(d+3)*CSD + t];
        a0 = fmaf(att_l[d+0], w0, a0);
        a1 = fmaf(att_l[d+1], w1, a1);
        a2 = fmaf(att_l[d+2], w2, a2);
        a3 = fmaf(att_l[d+3], w3, a3);
        b0 = fmaf(att_l[DOUT+d+0], w0, b0);
        b1 = fmaf(att_l[DOUT+d+1], w1, b1);
        b2 = fmaf(att_l[DOUT+d+2], w2, b2);
        b3 = fmaf(att_l[DOUT+d+3], w3, b3);
    }
    float bb = bout[t];
    out[(size_t)ib*CSD + t]     = bb + ((a0+a1)+(a2+a3));
    out[(size_t)(ib+1)*CSD + t] = bb + ((b0+b1)+(b2+b3));
}

extern "C" void kernel_launch(void* const* d_in, const int* in_sizes, int n_in,
                              void* d_out, int out_size, void* d_ws, size_t ws_size,
                              hipStream_t stream)
{
    const float* s   = (const float*)d_in[0];
    const float* z   = (const float*)d_in[1];
    const float* R   = (const float*)d_in[2];
    const float* tv  = (const float*)d_in[3];
    const float* Wq  = (const float*)d_in[4];
    const float* Wk  = (const float*)d_in[5];
    const float* Wv  = (const float*)d_in[6];
    const float* Wqp = (const float*)d_in[7];
    const float* Wkp = (const float*)d_in[8];
    const float* Wvp = (const float*)d_in[9];
    const float* Wb  = (const float*)d_in[10];
    const float* Wout= (const float*)d_in[11];
    const float* bout= (const float*)d_in[12];
    const float* sh  = (const float*)d_in[13];

    float* ws  = (float*)d_ws;
    float* q_  = ws;                 // 768*192
    float* k_  = q_  + 147456;       // 768*192
    float* v_  = k_  + 147456;       // 768*192
    float* gq_ = v_  + 147456;       // 768*144
    float* gk_ = gq_ + 110592;       // 768*144
    float* gv_ = gk_ + 110592;       // 768*288
    float* sqq_= gv_ + 221184;       // 768*12
    float* sqk_= sqq_ + 9216;        // 768*12
    float* a_  = sqk_ + 9216;        // 12*768*768
    float* att_= a_  + 7077888;      // 768*2112
    float* out = (float*)d_out;

    hipLaunchKernelGGL(k_proj,    dim3(NN),  dim3(384), 0, stream,
                       s,R,tv,Wq,Wk,Wv,Wqp,Wkp,Wvp, q_,k_,v_,gq_,gk_,gv_,sqq_,sqk_);
    hipLaunchKernelGGL(k_logits,  dim3(NN),  dim3(256), 0, stream,
                       z,Wb,sh,q_,k_,gq_,gk_,sqq_,sqk_, a_);
    hipLaunchKernelGGL(k_outputs, dim3(NN),  dim3(512), 0, stream,
                       a_,z,v_,gv_,R,tv, att_);
    hipLaunchKernelGGL(k_final,   dim3(NN/ROWS4), dim3(384), 0, stream,
                       att_,Wout,bout, out);
}

// Round 4
// 556.945 us; speedup vs baseline: 3.7175x; 1.6806x over previous
//
#include <hip/hip_runtime.h>
#include <hip/hip_bf16.h>

#define NN 768
#define CSD 384
#define CZD 128
#define HD 12
#define DOUT 2112

#define SCALE_SINGLE 0.25f
#define SCALE_FRAME (-0.11785113019775793f)   /* -1/sqrt(72) */

__device__ __forceinline__ float dot4f(float4 a, float4 b){
    return fmaf(a.x,b.x, fmaf(a.y,b.y, fmaf(a.z,b.z, a.w*b.w)));
}

// ---------------- K1: projections + frame apply ----------------
__global__ __launch_bounds__(384) void k_proj(
    const float* __restrict__ s, const float* __restrict__ R, const float* __restrict__ tv,
    const float* __restrict__ Wq, const float* __restrict__ Wk, const float* __restrict__ Wv,
    const float* __restrict__ Wqp, const float* __restrict__ Wkp, const float* __restrict__ Wvp,
    float* __restrict__ q, float* __restrict__ k, float* __restrict__ v,
    float* __restrict__ gq, float* __restrict__ gk, float* __restrict__ gv,
    float* __restrict__ sqq, float* __restrict__ sqk)
{
    __shared__ float s_l[CSD];
    __shared__ float praw[576];    // qp(144) kp(144) vp(288) raw local coords
    __shared__ float sq_pt[96];    // per-point squared norms (48 q, 48 k)
    int i = blockIdx.x, t = threadIdx.x;
    s_l[t] = s[(size_t)i*CSD + t];
    __syncthreads();

    int cols[3] = {t, t+384, t+768};
    const float* Wp[3]; int st[3], lc[3];
    #pragma unroll
    for (int m=0;m<3;m++){
        int c = cols[m];
        if (c < 192){ Wp[m]=Wq;  st[m]=192; lc[m]=c; }
        else if (c < 384){ Wp[m]=Wk;  st[m]=192; lc[m]=c-192; }
        else if (c < 576){ Wp[m]=Wv;  st[m]=192; lc[m]=c-384; }
        else if (c < 720){ Wp[m]=Wqp; st[m]=144; lc[m]=c-576; }
        else if (c < 864){ Wp[m]=Wkp; st[m]=144; lc[m]=c-720; }
        else { Wp[m]=Wvp; st[m]=288; lc[m]=c-864; }
    }
    float a0=0.f,a1=0.f,a2=0.f;
    #pragma unroll 8
    for (int r=0;r<CSD;r++){
        float sv = s_l[r];
        a0 = fmaf(sv, Wp[0][(size_t)r*st[0]+lc[0]], a0);
        a1 = fmaf(sv, Wp[1][(size_t)r*st[1]+lc[1]], a1);
        a2 = fmaf(sv, Wp[2][(size_t)r*st[2]+lc[2]], a2);
    }
    float av[3] = {a0,a1,a2};
    #pragma unroll
    for (int m=0;m<3;m++){
        int c = cols[m]; float val = av[m];
        if (c < 192) q[(size_t)i*192 + c] = val;
        else if (c < 384) k[(size_t)i*192 + (c-192)] = val;
        else if (c < 576) v[(size_t)i*192 + (c-384)] = val;
        else praw[c-576] = val;
    }
    __syncthreads();

    if (t < 192){
        const float* Ri = R + (size_t)i*9;
        float R00=Ri[0],R01=Ri[1],R02=Ri[2];
        float R10=Ri[3],R11=Ri[4],R12=Ri[5];
        float R20=Ri[6],R21=Ri[7],R22=Ri[8];
        float t0=tv[(size_t)i*3+0],t1=tv[(size_t)i*3+1],t2=tv[(size_t)i*3+2];
        int src; float* dst; int sqslot=-1;
        if (t < 48){ src = t*3; dst = gq + (size_t)i*144 + t*3; sqslot = t; }
        else if (t < 96){ int u=t-48; src = 144+u*3; dst = gk + (size_t)i*144 + u*3; sqslot = 48+u; }
        else { int u=t-96; src = 288+u*3; dst = gv + (size_t)i*288 + u*3; }
        float x=praw[src], y=praw[src+1], zc=praw[src+2];
        float g0 = fmaf(R00,x, fmaf(R01,y, fmaf(R02,zc, t0)));
        float g1 = fmaf(R10,x, fmaf(R11,y, fmaf(R12,zc, t1)));
        float g2 = fmaf(R20,x, fmaf(R21,y, fmaf(R22,zc, t2)));
        dst[0]=g0; dst[1]=g1; dst[2]=g2;
        if (sqslot >= 0) sq_pt[sqslot] = g0*g0 + g1*g1 + g2*g2;
    }
    __syncthreads();
    if (t < HD){
        float s1 = sq_pt[t*4]+sq_pt[t*4+1]+sq_pt[t*4+2]+sq_pt[t*4+3];
        float s2 = sq_pt[48+t*4]+sq_pt[48+t*4+1]+sq_pt[48+t*4+2]+sq_pt[48+t*4+3];
        sqq[(size_t)i*HD + t] = s1;
        sqk[(size_t)i*HD + t] = s2;
    }
}

// ---------------- K2: logits + softmax, LDS-staged z with XOR swizzle ----------------
// block = one i, 512 threads = 8 waves.
// All waves issue the z-tile prefetch (coverage needs 512 threads!).
// waves 0-3: pair term (z @ Wb) from swizzled LDS; waves 4-7: single+frame from L2.
__global__ __launch_bounds__(512) void k_logits(
    const float* __restrict__ z, const float* __restrict__ Wb, const float* __restrict__ scale_head,
    const float* __restrict__ q, const float* __restrict__ k,
    const float* __restrict__ gq, const float* __restrict__ gk,
    const float* __restrict__ sqq, const float* __restrict__ sqk,
    float* __restrict__ a)
{
    __shared__ float ztile[2][64][CZD];   // reused as S-exchange buffer after tile loop
    __shared__ float wbT[HD*CZD];         // [h][c]
    __shared__ float qloc[360];           // q(192) gq(144) sqq(12) sp(12)

    int i = blockIdx.x, t = threadIdx.x;
    int wave = t >> 6, lane = t & 63;

    for (int idx=t; idx<HD*CZD; idx+=512){
        int h = idx >> 7, c = idx & 127;
        wbT[idx] = Wb[(size_t)c*HD + h];
    }
    if (t < 192) qloc[t] = q[(size_t)i*192 + t];
    else if (t < 336) qloc[t] = gq[(size_t)i*144 + (t-192)];
    else if (t < 348) qloc[t] = sqq[(size_t)i*HD + (t-336)];
    else if (t < 360){
        int h = t-348;
        float shv = scale_head[h];
        float sp = (shv > 20.f) ? shv : log1pf(__expf(shv));
        qloc[t] = SCALE_FRAME * sp;
    }

    const char* zi = (const char*)(z + (size_t)i*NN*CZD);

    // stage one 64-row tile (32KB): linear LDS dest, inverse-swizzled global src
    // MUST be issued by all 512 threads (4 x 16B each).
#define STAGEL(JT, BUF) do { \
    const char* _zb = zi + (size_t)(JT)*32768; \
    char* _lb = (char*)&ztile[BUF][0][0]; \
    _Pragma("unroll") \
    for (int _m=0;_m<4;_m++){ \
        int _d = t*16 + _m*8192; \
        int _j = _d >> 9; \
        int _b = _d & 511; \
        int _sb = _b ^ ((_j & 31) << 4); \
        __builtin_amdgcn_global_load_lds((const __attribute__((address_space(1))) void*)(_zb + (size_t)_j*512 + _sb), \
            (__attribute__((address_space(3))) void*)(_lb + _d), 16, 0, 0); \
    } \
  } while(0)

    STAGEL(0, 0);

    int hg = (wave < 4) ? wave : (wave - 4);
    int h0 = hg * 3;
    float L[12][3];   // pair accum (waves 0-3) or single+frame (waves 4-7)

    __syncthreads();   // wbT/qloc visible; STAGE(0) drained

    {
        const float4* wb4 = (const float4*)wbT;
        const float4* qv4 = (const float4*)qloc;          // q  [h*4 + m]
        const float4* gq4 = (const float4*)(qloc + 192);  // gq [h*3 + m]
        int xoff = (lane & 31) << 4;

        for (int jt=0; jt<12; ++jt){
            int cur = jt & 1;
            if (jt+1 < 12) STAGEL(jt+1, cur^1);   // issued by ALL waves
            if (wave < 4){
                const char* zb = (const char*)&ztile[cur][0][0] + lane*512;
                float p0=0.f, p1=0.f, p2=0.f;
                #pragma unroll 8
                for (int c4=0; c4<32; ++c4){
                    float4 zv = *(const float4*)(zb + ((c4*16) ^ xoff));
                    p0 += dot4f(zv, wb4[(h0+0)*32 + c4]);
                    p1 += dot4f(zv, wb4[(h0+1)*32 + c4]);
                    p2 += dot4f(zv, wb4[(h0+2)*32 + c4]);
                }
                L[jt][0]=p0; L[jt][1]=p1; L[jt][2]=p2;
            } else {
                int jg = jt*64 + lane;
                const float4* kp  = (const float4*)(k  + (size_t)jg*192);
                const float4* gkp = (const float4*)(gk + (size_t)jg*144);
                #pragma unroll
                for (int hs=0; hs<3; ++hs){
                    int h = h0 + hs;
                    float sng = dot4f(qv4[h*4+0], kp[h*4+0]) + dot4f(qv4[h*4+1], kp[h*4+1])
                              + dot4f(qv4[h*4+2], kp[h*4+2]) + dot4f(qv4[h*4+3], kp[h*4+3]);
                    float fdot = dot4f(gq4[h*3+0], gkp[h*3+0]) + dot4f(gq4[h*3+1], gkp[h*3+1])
                               + dot4f(gq4[h*3+2], gkp[h*3+2]);
                    float d2 = qloc[336+h] + sqk[(size_t)jg*HD + h] - 2.0f*fdot;
                    L[jt][hs] = fmaf(SCALE_SINGLE, sng, qloc[348+h]*d2);
                }
            }
            __syncthreads();
        }
    }

    // exchange: S-waves deposit single+frame partials; pair-waves add
    float* S_l = (float*)ztile;   // tile loop done; safe to reuse
    if (wave >= 4){
        int base = (hg*64 + lane) * 37;
        #pragma unroll
        for (int jt=0; jt<12; ++jt)
            #pragma unroll
            for (int hs=0; hs<3; ++hs)
                S_l[base + jt*3 + hs] = L[jt][hs];
    }
    __syncthreads();
    if (wave < 4){
        int base = (hg*64 + lane) * 37;
        #pragma unroll
        for (int jt=0; jt<12; ++jt)
            #pragma unroll
            for (int hs=0; hs<3; ++hs)
                L[jt][hs] += S_l[base + jt*3 + hs];

        // in-wave softmax over j (768 = 12 tiles x 64 lanes)
        #pragma unroll
        for (int hs=0; hs<3; ++hs){
            float m = -1e30f;
            #pragma unroll
            for (int jt=0; jt<12; ++jt) m = fmaxf(m, L[jt][hs]);
            #pragma unroll
            for (int off=32; off; off>>=1) m = fmaxf(m, __shfl_xor(m, off));
            float ssum = 0.f;
            #pragma unroll
            for (int jt=0; jt<12; ++jt){ float e = __expf(L[jt][hs]-m); L[jt][hs]=e; ssum += e; }
            #pragma unroll
            for (int off=32; off; off>>=1) ssum += __shfl_xor(ssum, off);
            float inv = 1.0f/ssum;
            #pragma unroll
            for (int jt=0; jt<12; ++jt){
                a[((size_t)(h0+hs)*NN + i)*NN + jt*64 + lane] = L[jt][hs]*inv;
            }
        }
    }
#undef STAGEL
}

// ---------------- K3: o_z, o_s, so via LDS-staged tiles ----------------
__global__ __launch_bounds__(512) void k_outputs(
    const float* __restrict__ a, const float* __restrict__ z,
    const float* __restrict__ v, const float* __restrict__ gv,
    const float* __restrict__ R, const float* __restrict__ tv,
    float* __restrict__ att)
{
    __shared__ float a_l[HD][NN];
    __shared__ float ztile[2][32][CZD];
    __shared__ float so_l[288];
    int i = blockIdx.x, t = threadIdx.x;

    {
        float4* a_l4 = (float4*)&a_l[0][0];
        const float4* a4 = (const float4*)a;
        #pragma unroll
        for (int r=0;r<5;r++){
            int idx = t + r*512;
            if (idx < 2304){
                int h = idx/192, c = idx - h*192;
                a_l4[idx] = a4[(size_t)(h*NN + i)*192 + c];
            }
        }
    }

    const float* zi = z + (size_t)i*NN*CZD;

#define STAGE(JT, BUF) do { \
    const float* _s = zi + (size_t)(JT)*4096 + t*4; \
    float* _d = &ztile[BUF][0][0] + t*4; \
    __builtin_amdgcn_global_load_lds((const __attribute__((address_space(1))) void*)_s, \
        (__attribute__((address_space(3))) void*)_d, 16, 0, 0); \
    __builtin_amdgcn_global_load_lds((const __attribute__((address_space(1))) void*)(_s+2048), \
        (__attribute__((address_space(3))) void*)(_d+2048), 16, 0, 0); \
  } while(0)

    STAGE(0, 0);

    int hs = 0;
    const float4* gsrc = nullptr;
    int gstride = 0;
    if (t < 384){ hs = t>>5; }
    else if (t < 432){ int u=t-384; hs = u>>2; gsrc = (const float4*)v  + hs*4 + (u&3); gstride = 48; }
    else if (t < 504){ int u=t-432; hs = u/6;  gsrc = (const float4*)gv + hs*6 + (u%6); gstride = 72; }
    float4 acc = {0.f,0.f,0.f,0.f};
    int c4 = t & 31;

    __syncthreads();

    for (int jt=0; jt<24; ++jt){
        int cur = jt & 1;
        if (jt+1 < 24) STAGE(jt+1, cur^1);
        if (t < 384){
            const float4* arow4 = (const float4*)&a_l[hs][0];
            float4 af[8];
            #pragma unroll
            for (int m=0;m<8;m++) af[m] = arow4[jt*8 + m];
            const float4* zt4 = (const float4*)&ztile[cur][0][0];
            #pragma unroll
            for (int jj=0;jj<32;jj++){
                float aw = ((const float*)af)[jj];
                float4 zv = zt4[jj*32 + c4];
                acc.x = fmaf(aw, zv.x, acc.x);
                acc.y = fmaf(aw, zv.y, acc.y);
                acc.z = fmaf(aw, zv.z, acc.z);
                acc.w = fmaf(aw, zv.w, acc.w);
            }
        } else if (t < 504){
            const float* arow = &a_l[hs][0];
            #pragma unroll
            for (int jj=0;jj<32;jj++){
                int j = jt*32 + jj;
                float aw = arow[j];
                float4 sv = gsrc[(size_t)j*gstride];
                acc.x = fmaf(aw, sv.x, acc.x);
                acc.y = fmaf(aw, sv.y, acc.y);
                acc.z = fmaf(aw, sv.z, acc.z);
                acc.w = fmaf(aw, sv.w, acc.w);
            }
        }
        __syncthreads();
    }

    if (t < 384){
        float4* dst = (float4*)(att + (size_t)i*DOUT + 192) + (hs*32 + c4);
        *dst = acc;
    } else if (t < 432){
        int u = t-384;
        float4* dst = (float4*)(att + (size_t)i*DOUT) + u;
        *dst = acc;
    } else if (t < 504){
        int u = t-432;
        ((float4*)so_l)[u] = acc;
    }
    __syncthreads();
    if (t < 96){
        int h = t >> 3, p = t & 7;
        float d0 = so_l[h*24+p*3+0] - tv[(size_t)i*3+0];
        float d1 = so_l[h*24+p*3+1] - tv[(size_t)i*3+1];
        float d2 = so_l[h*24+p*3+2] - tv[(size_t)i*3+2];
        const float* Ri = R + (size_t)i*9;
        float l0 = fmaf(Ri[0],d0, fmaf(Ri[3],d1, Ri[6]*d2));
        float l1 = fmaf(Ri[1],d0, fmaf(Ri[4],d1, Ri[7]*d2));
        float l2 = fmaf(Ri[2],d0, fmaf(Ri[5],d1, Ri[8]*d2));
        size_t base = (size_t)i*DOUT;
        att[base + 1728 + p*36 + h*3 + 0] = l0;
        att[base + 1728 + p*36 + h*3 + 1] = l1;
        att[base + 1728 + p*36 + h*3 + 2] = l2;
        att[base + 2016 + p*12 + h] = sqrtf(l0*l0 + l1*l1 + l2*l2);
    }
#undef STAGE
}

// ---------------- K4: final projection att @ Wout + bout ----------------
#define ROWS4 2
__global__ __launch_bounds__(384) void k_final(
    const float* __restrict__ att, const float* __restrict__ Wout, const float* __restrict__ bout,
    float* __restrict__ out)
{
    __shared__ float att_l[ROWS4*DOUT];
    int ib = blockIdx.x * ROWS4, t = threadIdx.x;
    for (int idx=t; idx<ROWS4*DOUT; idx+=384){
        att_l[idx] = att[(size_t)ib*DOUT + idx];
    }
    __syncthreads();
    float a0=0.f,a1=0.f,a2=0.f,a3=0.f;
    float b0=0.f,b1=0.f,b2=0.f,b3=0.f;
    #pragma unroll 4
    for (int d=0; d<DOUT; d+=4){
        float w0 = Wout[(size_t)(d+0)*CSD + t];
        float w1 = Wout[(size_t)(d+1)*CSD + t];
        float w2 = Wout[(size_t)(d+2)*CSD + t];
        float w3 = Wout[(size_t)(d+3)*CSD + t];
        a0 = fmaf(att_l[d+0], w0, a0);
        a1 = fmaf(att_l[d+1], w1, a1);
        a2 = fmaf(att_l[d+2], w2, a2);
        a3 = fmaf(att_l[d+3], w3, a3);
        b0 = fmaf(att_l[DOUT+d+0], w0, b0);
        b1 = fmaf(att_l[DOUT+d+1], w1, b1);
        b2 = fmaf(att_l[DOUT+d+2], w2, b2);
        b3 = fmaf(att_l[DOUT+d+3], w3, b3);
    }
    float bb = bout[t];
    out[(size_t)ib*CSD + t]     = bb + ((a0+a1)+(a2+a3));
    out[(size_t)(ib+1)*CSD + t] = bb + ((b0+b1)+(b2+b3));
}

extern "C" void kernel_launch(void* const* d_in, const int* in_sizes, int n_in,
                              void* d_out, int out_size, void* d_ws, size_t ws_size,
                              hipStream_t stream)
{
    const float* s   = (const float*)d_in[0];
    const float* z   = (const float*)d_in[1];
    const float* R   = (const float*)d_in[2];
    const float* tv  = (const float*)d_in[3];
    const float* Wq  = (const float*)d_in[4];
    const float* Wk  = (const float*)d_in[5];
    const float* Wv  = (const float*)d_in[6];
    const float* Wqp = (const float*)d_in[7];
    const float* Wkp = (const float*)d_in[8];
    const float* Wvp = (const float*)d_in[9];
    const float* Wb  = (const float*)d_in[10];
    const float* Wout= (const float*)d_in[11];
    const float* bout= (const float*)d_in[12];
    const float* sh  = (const float*)d_in[13];

    float* ws  = (float*)d_ws;
    float* q_  = ws;                 // 768*192
    float* k_  = q_  + 147456;       // 768*192
    float* v_  = k_  + 147456;       // 768*192
    float* gq_ = v_  + 147456;       // 768*144
    float* gk_ = gq_ + 110592;       // 768*144
    float* gv_ = gk_ + 110592;       // 768*288
    float* sqq_= gv_ + 221184;       // 768*12
    float* sqk_= sqq_ + 9216;        // 768*12
    float* a_  = sqk_ + 9216;        // 12*768*768
    float* att_= a_  + 7077888;      // 768*2112
    float* out = (float*)d_out;

    hipLaunchKernelGGL(k_proj,    dim3(NN),  dim3(384), 0, stream,
                       s,R,tv,Wq,Wk,Wv,Wqp,Wkp,Wvp, q_,k_,v_,gq_,gk_,gv_,sqq_,sqk_);
    hipLaunchKernelGGL(k_logits,  dim3(NN),  dim3(512), 0, stream,
                       z,Wb,sh,q_,k_,gq_,gk_,sqq_,sqk_, a_);
    hipLaunchKernelGGL(k_outputs, dim3(NN),  dim3(512), 0, stream,
                       a_,z,v_,gv_,R,tv, att_);
    hipLaunchKernelGGL(k_final,   dim3(NN/ROWS4), dim3(384), 0, stream,
                       att_,Wout,bout, out);
}